// Round 3
// baseline (1506.895 us; speedup 1.0000x reference)
//
#include <hip/hip_runtime.h>
#include <hip/hip_bf16.h>

#define NN 100000
#define DD 128
#define VV 3
#define EE 500000

typedef unsigned short u16;
typedef unsigned int u32;

__device__ __forceinline__ float bf2f(u16 u) {
    return __uint_as_float(((u32)u) << 16);
}
__device__ __forceinline__ u16 f2bf(float f) {
    u32 x = __float_as_uint(f);
    u32 r = (x + 0x7fffu + ((x >> 16) & 1u)) >> 16;
    return (u16)r;
}

// packed bf16 atomic add of (f0,f1) at 4B-aligned bf16 pair
__device__ __forceinline__ void atomAddBf16x2(u16* addr, float f0, float f1) {
#if __has_builtin(__builtin_amdgcn_global_atomic_fadd_v2bf16)
    typedef short v2s __attribute__((ext_vector_type(2)));
    typedef v2s __attribute__((address_space(1)))* v2s_gp;
    v2s v;
    v.x = (short)f2bf(f0);
    v.y = (short)f2bf(f1);
    __builtin_amdgcn_global_atomic_fadd_v2bf16((v2s_gp)(void*)addr, v);
#else
    u32* p = (u32*)addr;
    u32 old = *(volatile u32*)p;
    while (true) {
        float lo = bf2f((u16)(old & 0xffffu)) + f0;
        float hi = bf2f((u16)(old >> 16)) + f1;
        u32 nv = (u32)f2bf(lo) | ((u32)f2bf(hi) << 16);
        u32 prev = atomicCAS(p, old, nv);
        if (prev == old) break;
        old = prev;
    }
#endif
}

// ---- generic GEMM accumulate: acc[4][4] += X[32 rows][K] * W[64 krows][BN] ----
template<int XSTR, int WSTR>
__device__ __forceinline__ void gemm16(float acc[4][4], const float* Xs,
                                       const float* Ws, int n0, int o0, int kbase) {
    #pragma unroll 4
    for (int kk = 0; kk < 64; kk += 4) {
        float4 w0 = *reinterpret_cast<const float4*>(Ws + (kk + 0) * WSTR + o0);
        float4 w1 = *reinterpret_cast<const float4*>(Ws + (kk + 1) * WSTR + o0);
        float4 w2 = *reinterpret_cast<const float4*>(Ws + (kk + 2) * WSTR + o0);
        float4 w3 = *reinterpret_cast<const float4*>(Ws + (kk + 3) * WSTR + o0);
        #pragma unroll
        for (int i = 0; i < 4; ++i) {
            float4 x = *reinterpret_cast<const float4*>(Xs + (n0 + i) * XSTR + kbase + kk);
            acc[i][0] = fmaf(x.x, w0.x, fmaf(x.y, w1.x, fmaf(x.z, w2.x, fmaf(x.w, w3.x, acc[i][0]))));
            acc[i][1] = fmaf(x.x, w0.y, fmaf(x.y, w1.y, fmaf(x.z, w2.y, fmaf(x.w, w3.y, acc[i][1]))));
            acc[i][2] = fmaf(x.x, w0.z, fmaf(x.y, w1.z, fmaf(x.z, w2.z, fmaf(x.w, w3.z, acc[i][2]))));
            acc[i][3] = fmaf(x.x, w0.w, fmaf(x.y, w1.w, fmaf(x.z, w2.w, fmaf(x.w, w3.w, acc[i][3]))));
        }
    }
}

// stage 64x128 fp32 weights (global, row stride 128) into LDS, row stride WSTR
template<int WSTR, int NT>
__device__ __forceinline__ void stage_w_f32(float* Ws, const float* __restrict__ src, int tid) {
    #pragma unroll
    for (int rep = 0; rep < 2048 / NT; ++rep) {
        int flat = rep * NT + tid;          // 0..2047 float4 chunks
        int kk = flat >> 5;
        int c4 = flat & 31;
        float4 q = *reinterpret_cast<const float4*>(src + kk * 128 + c4 * 4);
        *reinterpret_cast<float4*>(Ws + kk * WSTR + c4 * 4) = q;
    }
}

// stage 32x128 fp32 rows (row stride 128) into LDS [32][XSTR]
template<int XSTR, int NT>
__device__ __forceinline__ void stage_x_f32(float* Xs, const float* __restrict__ src, int tid) {
    #pragma unroll
    for (int rep = 0; rep < 1024 / NT; ++rep) {
        int flat = rep * NT + tid;          // 0..1023 float4 chunks
        int n = flat >> 5;
        int c4 = flat & 31;
        float4 q = *reinterpret_cast<const float4*>(src + (size_t)n * 128 + c4 * 4);
        *reinterpret_cast<float4*>(Xs + n * XSTR + c4 * 4) = q;
    }
}

// stage 32x128 bf16 rows (row stride 128) into LDS fp32 [32][XSTR]
template<int XSTR, int NT>
__device__ __forceinline__ void stage_x_bf16(float* Xs, const u16* __restrict__ src, int tid) {
    #pragma unroll
    for (int rep = 0; rep < 512 / NT; ++rep) {
        int flat = rep * NT + tid;          // 0..511 : uint4 chunks of 8 bf16
        int n = flat >> 4;
        int c8 = flat & 15;
        uint4 q = *reinterpret_cast<const uint4*>(src + (size_t)n * 128 + c8 * 8);
        float* d = Xs + n * XSTR + c8 * 8;
        d[0] = bf2f((u16)(q.x & 0xffffu)); d[1] = bf2f((u16)(q.x >> 16));
        d[2] = bf2f((u16)(q.y & 0xffffu)); d[3] = bf2f((u16)(q.y >> 16));
        d[4] = bf2f((u16)(q.z & 0xffffu)); d[5] = bf2f((u16)(q.z >> 16));
        d[6] = bf2f((u16)(q.w & 0xffffu)); d[7] = bf2f((u16)(q.w >> 16));
    }
}

// ---------------- prep: Wsf = selfW @ fusW_top ; c1 = selfb @ fusW_top + fusb ----
__global__ void prep_kernel(const float* __restrict__ selfW, const float* __restrict__ selfb,
                            const float* __restrict__ fusW, const float* __restrict__ fusb,
                            float* __restrict__ Wsf, float* __restrict__ c1) {
    int o = threadIdx.x;
    int k = blockIdx.x;
    if (k < 128) {
        float acc = 0.f;
        for (int m = 0; m < 128; ++m)
            acc += selfW[k * 128 + m] * fusW[m * 128 + o];
        Wsf[k * 128 + o] = acc;
    } else {
        float acc = 0.f;
        for (int m = 0; m < 128; ++m)
            acc += selfb[m] * fusW[m * 128 + o];
        c1[o] = acc + fusb[o];
    }
}

// ---------------- scatter: aggB[v,dst,:] += bf16(w*feat[src,:]), wsum[v,dst] += w ----
__global__ __launch_bounds__(256) void scatter_kernel(
        const int* __restrict__ esrc, const int* __restrict__ edst,
        const float* __restrict__ ew, const float* __restrict__ feat,
        u16* __restrict__ aggB, float* __restrict__ wsum) {
    long long t = (long long)blockIdx.x * 256 + threadIdx.x;
    int lane = (int)(t & 31);
    int eg = (int)(t >> 5);                 // global edge id < 1.5M
    int v = eg / EE;
    int src = 0, dst = 0; float w = 0.f;
    if (lane == 0) {
        src = esrc[eg]; dst = edst[eg]; w = ew[eg];
    }
    src = __shfl(src, 0, 32);
    dst = __shfl(dst, 0, 32);
    w   = __shfl(w, 0, 32);
    const float* fr = feat + (size_t)src * DD + lane * 4;
    float4 q = *reinterpret_cast<const float4*>(fr);
    u16* outp = aggB + ((size_t)v * NN + dst) * DD + lane * 4;
    atomAddBf16x2(outp,     w * q.x, w * q.y);
    atomAddBf16x2(outp + 2, w * q.z, w * q.w);
    if (lane == 0) atomicAdd(wsum + v * NN + dst, w);
}

// ---------------- label-aware attention -> node_att (fp32 ws), class_probs (fp32 out) ----
__global__ __launch_bounds__(256) void label_kernel(
        const float* __restrict__ feat, const float* __restrict__ clsW, const float* __restrict__ clsb,
        const float* __restrict__ attW1, const float* __restrict__ attb1,
        const float* __restrict__ attW2, const float* __restrict__ attb2,
        const float* __restrict__ att_bias,
        float* __restrict__ node_att, float* __restrict__ probs_out) {
    __shared__ float Xs[32][132];
    __shared__ float Ws[64][132];
    int tid = threadIdx.x;
    int row0 = blockIdx.x * 32;
    stage_x_f32<132, 256>(&Xs[0][0], feat + (size_t)row0 * DD, tid);
    int to = tid & 31, tn = tid >> 5;
    int o0 = to * 4, n0 = tn * 4;
    float acc[4][4] = {};
    for (int half = 0; half < 2; ++half) {
        __syncthreads();
        // Ws[kk][o] = attW1[c][half*64+kk][h], o = c*64+h
        #pragma unroll
        for (int rep = 0; rep < 8; ++rep) {
            int flat = rep * 256 + tid;     // 0..2047 float4 chunks
            int kk = flat >> 5, o4 = flat & 31;
            int o = o4 * 4;
            int c = o >> 6, h = o & 63;
            int k = half * 64 + kk;
            float4 q = *reinterpret_cast<const float4*>(attW1 + (size_t)(c * 128 + k) * 64 + h);
            *reinterpret_cast<float4*>(&Ws[kk][o]) = q;
        }
        __syncthreads();
        gemm16<132, 132>(acc, &Xs[0][0], &Ws[0][0], n0, o0, half * 64);
    }
    int c = o0 >> 6, h0 = o0 & 63;
    float b1j[4], w2j[4];
    #pragma unroll
    for (int j = 0; j < 4; ++j) {
        b1j[j] = attb1[c * 64 + h0 + j];
        w2j[j] = attW2[c * 64 + h0 + j];
    }
    float part[4];
    #pragma unroll
    for (int i = 0; i < 4; ++i) {
        float s = 0.f;
        #pragma unroll
        for (int j = 0; j < 4; ++j) {
            float hv = acc[i][j] + b1j[j];
            hv = hv > 0.f ? hv : 0.f;
            s += hv * w2j[j];
        }
        part[i] = s;
    }
    __syncthreads();
    float* red = &Ws[0][0];          // [32][33]
    float* Ssc = red + 32 * 33;      // [32][2]
    float* Lsc = Ssc + 64;           // [32][2]
    #pragma unroll
    for (int i = 0; i < 4; ++i) red[(n0 + i) * 33 + to] = part[i];
    __syncthreads();
    if (tid < 64) {
        int n = tid >> 1, cc = tid & 1;
        float l = 0.f;
        for (int k = 0; k < 128; k += 4) {
            float4 x = *reinterpret_cast<const float4*>(&Xs[n][k]);
            l += x.x * clsW[(k + 0) * 2 + cc];
            l += x.y * clsW[(k + 1) * 2 + cc];
            l += x.z * clsW[(k + 2) * 2 + cc];
            l += x.w * clsW[(k + 3) * 2 + cc];
        }
        Lsc[n * 2 + cc] = l + clsb[cc];
        float s = 0.f;
        for (int u = 0; u < 16; ++u) s += red[n * 33 + cc * 16 + u];
        s += attb2[cc];
        Ssc[n * 2 + cc] = 1.f / (1.f + expf(-s));
    }
    __syncthreads();
    if (tid < 32) {
        int n = tid;
        float l0 = Lsc[n * 2], l1 = Lsc[n * 2 + 1];
        float m = fmaxf(l0, l1);
        float e0 = expf(l0 - m), e1 = expf(l1 - m);
        float inv = 1.f / (e0 + e1);
        float p0 = e0 * inv, p1 = e1 * inv;
        float na = p0 * Ssc[n * 2] + p1 * Ssc[n * 2 + 1] + att_bias[0];
        int row = row0 + n;
        node_att[row] = na;
        probs_out[row * 2]     = p0;
        probs_out[row * 2 + 1] = p1;
    }
}

// ---------------- per-view: agg = aggB@relW + wsum*relb ; view_out = sigmoid(agg@gateW+gb)*agg ----
__global__ __launch_bounds__(256) void relgate_kernel(
        const float* __restrict__ relW, const float* __restrict__ relb,
        const float* __restrict__ gateW, const float* __restrict__ gateb,
        u16* __restrict__ aggB, const float* __restrict__ wsum) {
    __shared__ float Xs[32][128];
    __shared__ float Ws[64][132];
    int tid = threadIdx.x;
    int v = blockIdx.y;
    int row0 = blockIdx.x * 32;
    u16* base = aggB + ((size_t)v * NN + row0) * DD;
    stage_x_bf16<128, 256>(&Xs[0][0], base, tid);
    int to = tid & 31, tn = tid >> 5;
    int o0 = to * 4, n0 = tn * 4;
    float acc[4][4] = {};
    const float* W1 = relW + (size_t)v * DD * DD;
    for (int half = 0; half < 2; ++half) {
        __syncthreads();
        stage_w_f32<132, 256>(&Ws[0][0], W1 + half * 64 * DD, tid);
        __syncthreads();
        gemm16<128, 132>(acc, &Xs[0][0], &Ws[0][0], n0, o0, half * 64);
    }
    float wsn[4], rb[4];
    #pragma unroll
    for (int i = 0; i < 4; ++i) wsn[i] = wsum[v * NN + row0 + n0 + i];
    #pragma unroll
    for (int j = 0; j < 4; ++j) rb[j] = relb[v * DD + o0 + j];
    #pragma unroll
    for (int i = 0; i < 4; ++i)
        #pragma unroll
        for (int j = 0; j < 4; ++j) acc[i][j] += wsn[i] * rb[j];
    __syncthreads();
    #pragma unroll
    for (int i = 0; i < 4; ++i)
        *reinterpret_cast<float4*>(&Xs[n0 + i][o0]) = make_float4(acc[i][0], acc[i][1], acc[i][2], acc[i][3]);
    float acc2[4][4] = {};
    const float* W2 = gateW + (size_t)v * DD * DD;
    for (int half = 0; half < 2; ++half) {
        __syncthreads();
        stage_w_f32<132, 256>(&Ws[0][0], W2 + half * 64 * DD, tid);
        __syncthreads();
        gemm16<128, 132>(acc2, &Xs[0][0], &Ws[0][0], n0, o0, half * 64);
    }
    float gb[4];
    #pragma unroll
    for (int j = 0; j < 4; ++j) gb[j] = gateb[v * DD + o0 + j];
    #pragma unroll
    for (int i = 0; i < 4; ++i) {
        float g0 = 1.f / (1.f + expf(-(acc2[i][0] + gb[0])));
        float g1 = 1.f / (1.f + expf(-(acc2[i][1] + gb[1])));
        float g2 = 1.f / (1.f + expf(-(acc2[i][2] + gb[2])));
        float g3 = 1.f / (1.f + expf(-(acc2[i][3] + gb[3])));
        ushort4 r;
        r.x = f2bf(g0 * acc[i][0]); r.y = f2bf(g1 * acc[i][1]);
        r.z = f2bf(g2 * acc[i][2]); r.w = f2bf(g3 * acc[i][3]);
        *reinterpret_cast<ushort4*>(base + (size_t)(n0 + i) * DD + o0) = r;
    }
}

// ---------------- view attention scores: vscores[v][n] ----
__global__ __launch_bounds__(128) void vatt_kernel(
        const u16* __restrict__ aggB, const float* __restrict__ view_pref,
        const float* __restrict__ vattW1, const float* __restrict__ vattb1,
        const float* __restrict__ vattW2, const float* __restrict__ vattb2,
        float* __restrict__ vscores) {
    __shared__ float Xs[32][132];
    __shared__ float Ws[128][68];
    int tid = threadIdx.x;
    int v = blockIdx.y;
    int row0 = blockIdx.x * 32;
    const u16* base = aggB + ((size_t)v * NN + row0) * DD;
    #pragma unroll
    for (int rep = 0; rep < 4; ++rep) {
        int flat = rep * 128 + tid;        // 0..511 uint4 chunks of 8 bf16
        int n = flat >> 4, c8 = flat & 15;
        uint4 q = *reinterpret_cast<const uint4*>(base + (size_t)n * DD + c8 * 8);
        float4 pa = *reinterpret_cast<const float4*>(view_pref + v * DD + c8 * 8);
        float4 pb = *reinterpret_cast<const float4*>(view_pref + v * DD + c8 * 8 + 4);
        float* d = &Xs[n][c8 * 8];
        d[0] = bf2f((u16)(q.x & 0xffffu)) * pa.x; d[1] = bf2f((u16)(q.x >> 16)) * pa.y;
        d[2] = bf2f((u16)(q.y & 0xffffu)) * pa.z; d[3] = bf2f((u16)(q.y >> 16)) * pa.w;
        d[4] = bf2f((u16)(q.z & 0xffffu)) * pb.x; d[5] = bf2f((u16)(q.z >> 16)) * pb.y;
        d[6] = bf2f((u16)(q.w & 0xffffu)) * pb.z; d[7] = bf2f((u16)(q.w >> 16)) * pb.w;
    }
    #pragma unroll
    for (int rep = 0; rep < 16; ++rep) {
        int flat = rep * 128 + tid;     // 0..2047 float4 chunks
        int k = flat >> 4, c4 = flat & 15;
        float4 q = *reinterpret_cast<const float4*>(vattW1 + k * 64 + c4 * 4);
        *reinterpret_cast<float4*>(&Ws[k][c4 * 4]) = q;
    }
    __syncthreads();
    int to = tid & 15, tn = tid >> 4;    // o0 in [0,64), n0 in [0,32)
    int o0 = to * 4, n0 = tn * 4;
    float acc[4][4] = {};
    gemm16<132, 68>(acc, &Xs[0][0], &Ws[0][0], n0, o0, 0);
    gemm16<132, 68>(acc, &Xs[0][0], &Ws[64][0], n0, o0, 64);
    float b1[4], w2[4];
    #pragma unroll
    for (int j = 0; j < 4; ++j) {
        b1[j] = vattb1[o0 + j];
        w2[j] = vattW2[o0 + j];
    }
    float part[4];
    #pragma unroll
    for (int i = 0; i < 4; ++i) {
        float s = 0.f;
        #pragma unroll
        for (int j = 0; j < 4; ++j) {
            float hv = acc[i][j] + b1[j];
            hv = hv > 0.f ? hv : 0.f;
            s += hv * w2[j];
        }
        part[i] = s;
    }
    __syncthreads();
    float* red = &Ws[0][0];   // [32][17]
    #pragma unroll
    for (int i = 0; i < 4; ++i) red[(n0 + i) * 17 + to] = part[i];
    __syncthreads();
    if (tid < 32) {
        float s = 0.f;
        for (int u = 0; u < 16; ++u) s += red[tid * 17 + u];
        vscores[(size_t)v * NN + row0 + tid] = s + vattb2[0];
    }
}

// ---------------- combine: weighted = node_att * sum_v softmax_v(vsc) * view_out (into aggB[0]) ----
__global__ __launch_bounds__(256) void combine_kernel(
        u16* __restrict__ aggB, const float* __restrict__ vscores,
        const float* __restrict__ node_att) {
    int t = blockIdx.x * 256 + threadIdx.x;   // < 3.2M
    int n = t >> 5, c4 = t & 31;
    float s0 = vscores[n], s1 = vscores[NN + n], s2 = vscores[2 * NN + n];
    float m = fmaxf(s0, fmaxf(s1, s2));
    float e0 = expf(s0 - m), e1 = expf(s1 - m), e2 = expf(s2 - m);
    float inv = 1.f / (e0 + e1 + e2);
    float w0 = e0 * inv, w1 = e1 * inv, w2 = e2 * inv;
    float na = node_att[n];
    size_t off = (size_t)n * DD + c4 * 4;
    ushort4 q0 = *reinterpret_cast<const ushort4*>(aggB + off);
    ushort4 q1 = *reinterpret_cast<const ushort4*>(aggB + (size_t)NN * DD + off);
    ushort4 q2 = *reinterpret_cast<const ushort4*>(aggB + 2 * (size_t)NN * DD + off);
    ushort4 r;
    r.x = f2bf((bf2f(q0.x) * w0 + bf2f(q1.x) * w1 + bf2f(q2.x) * w2) * na);
    r.y = f2bf((bf2f(q0.y) * w0 + bf2f(q1.y) * w1 + bf2f(q2.y) * w2) * na);
    r.z = f2bf((bf2f(q0.z) * w0 + bf2f(q1.z) * w1 + bf2f(q2.z) * w2) * na);
    r.w = f2bf((bf2f(q0.w) * w0 + bf2f(q1.w) * w1 + bf2f(q2.w) * w2) * na);
    *reinterpret_cast<ushort4*>(aggB + off) = r;
}

// ---------------- final: fused = relu(feat@Wsf + weighted@fusW_bot + c1); out = LN(fused + feat@featW + featb) ----
__global__ __launch_bounds__(256) void final_kernel(
        const float* __restrict__ feat, const u16* __restrict__ weightedB,
        const float* __restrict__ Wsf, const float* __restrict__ c1,
        const float* __restrict__ fusW, const float* __restrict__ featW,
        const float* __restrict__ featb, const float* __restrict__ ln_g,
        const float* __restrict__ ln_b, float* __restrict__ outp) {
    __shared__ float Xs[32][128];
    __shared__ float Ws[64][128];
    int tid = threadIdx.x;
    int row0 = blockIdx.x * 32;
    stage_x_f32<128, 256>(&Xs[0][0], feat + (size_t)row0 * DD, tid);
    int to = tid & 31, tn = tid >> 5;
    int o0 = to * 4, n0 = tn * 4;
    float acc1[4][4] = {}, acc2[4][4] = {};
    for (int half = 0; half < 2; ++half) {
        __syncthreads();
        stage_w_f32<128, 256>(&Ws[0][0], Wsf + half * 64 * 128, tid);
        __syncthreads();
        gemm16<128, 128>(acc1, &Xs[0][0], &Ws[0][0], n0, o0, half * 64);
    }
    for (int half = 0; half < 2; ++half) {
        __syncthreads();
        stage_w_f32<128, 256>(&Ws[0][0], featW + half * 64 * 128, tid);
        __syncthreads();
        gemm16<128, 128>(acc2, &Xs[0][0], &Ws[0][0], n0, o0, half * 64);
    }
    __syncthreads();   // all reads of Xs(feat) done; reuse for weighted
    stage_x_bf16<128, 256>(&Xs[0][0], weightedB + (size_t)row0 * DD, tid);
    for (int half = 0; half < 2; ++half) {
        __syncthreads();
        stage_w_f32<128, 256>(&Ws[0][0], fusW + (size_t)(128 + half * 64) * 128, tid);
        __syncthreads();
        gemm16<128, 128>(acc1, &Xs[0][0], &Ws[0][0], n0, o0, half * 64);
    }
    float c1j[4], fbj[4], gj[4], bj[4];
    #pragma unroll
    for (int j = 0; j < 4; ++j) {
        c1j[j] = c1[o0 + j];
        fbj[j] = featb[o0 + j];
        gj[j]  = ln_g[o0 + j];
        bj[j]  = ln_b[o0 + j];
    }
    float val[4][4];
    #pragma unroll
    for (int i = 0; i < 4; ++i)
        #pragma unroll
        for (int j = 0; j < 4; ++j) {
            float f = acc1[i][j] + c1j[j];
            f = f > 0.f ? f : 0.f;
            val[i][j] = f + acc2[i][j] + fbj[j];
        }
    __syncthreads();
    float* red_s = &Ws[0][0];            // [32][33]
    float* red_q = red_s + 32 * 33;      // [32][33]
    float* mus   = red_q + 32 * 33;      // [32]
    float* rss   = mus + 32;             // [32]
    #pragma unroll
    for (int i = 0; i < 4; ++i) {
        float s = 0.f, q = 0.f;
        #pragma unroll
        for (int j = 0; j < 4; ++j) { s += val[i][j]; q += val[i][j] * val[i][j]; }
        red_s[(n0 + i) * 33 + to] = s;
        red_q[(n0 + i) * 33 + to] = q;
    }
    __syncthreads();
    if (tid < 32) {
        float s = 0.f, q = 0.f;
        for (int u = 0; u < 32; ++u) { s += red_s[tid * 33 + u]; q += red_q[tid * 33 + u]; }
        float mu = s / 128.f;
        float var = q / 128.f - mu * mu;
        mus[tid] = mu;
        rss[tid] = rsqrtf(var + 1e-5f);
    }
    __syncthreads();
    #pragma unroll
    for (int i = 0; i < 4; ++i) {
        float mu = mus[n0 + i], rs = rss[n0 + i];
        float4 o;
        o.x = (val[i][0] - mu) * rs * gj[0] + bj[0];
        o.y = (val[i][1] - mu) * rs * gj[1] + bj[1];
        o.z = (val[i][2] - mu) * rs * gj[2] + bj[2];
        o.w = (val[i][3] - mu) * rs * gj[3] + bj[3];
        *reinterpret_cast<float4*>(outp + (size_t)(row0 + n0 + i) * DD + o0) = o;
    }
}

extern "C" void kernel_launch(void* const* d_in, const int* in_sizes, int n_in,
                              void* d_out, int out_size, void* d_ws, size_t ws_size,
                              hipStream_t stream) {
    (void)in_sizes; (void)n_in; (void)out_size; (void)ws_size;
    const float* feat      = (const float*)d_in[0];
    const int*   esrc      = (const int*)d_in[1];
    const int*   edst      = (const int*)d_in[2];
    const float* ew        = (const float*)d_in[3];
    const float* clsW      = (const float*)d_in[4];
    const float* clsb      = (const float*)d_in[5];
    const float* attW1     = (const float*)d_in[6];
    const float* attb1     = (const float*)d_in[7];
    const float* attW2     = (const float*)d_in[8];
    const float* attb2     = (const float*)d_in[9];
    const float* att_bias  = (const float*)d_in[10];
    const float* relW      = (const float*)d_in[11];
    const float* relb      = (const float*)d_in[12];
    const float* gateW     = (const float*)d_in[13];
    const float* gateb     = (const float*)d_in[14];
    const float* view_pref = (const float*)d_in[15];
    const float* vattW1    = (const float*)d_in[16];
    const float* vattb1    = (const float*)d_in[17];
    const float* vattW2    = (const float*)d_in[18];
    const float* vattb2    = (const float*)d_in[19];
    const float* selfW     = (const float*)d_in[20];
    const float* selfb     = (const float*)d_in[21];
    const float* featW     = (const float*)d_in[22];
    const float* featb     = (const float*)d_in[23];
    const float* fusW      = (const float*)d_in[24];
    const float* fusb      = (const float*)d_in[25];
    const float* ln_g      = (const float*)d_in[26];
    const float* ln_b      = (const float*)d_in[27];

    // workspace layout (~80 MiB total):
    u16*   aggB = (u16*)d_ws;                                   // [3][N][128] bf16
    float* wsum = (float*)(aggB + (size_t)VV * NN * DD);        // [3][N] fp32
    float* natt = wsum + (size_t)VV * NN;                       // [N]
    float* vsc  = natt + NN;                                    // [3][N]
    float* Wsf  = vsc + (size_t)VV * NN;                        // [128][128] fp32
    float* c1   = Wsf + DD * DD;                                // [128]
    float* outp  = (float*)d_out;
    float* probs = outp + (size_t)NN * DD;

    hipMemsetAsync(d_ws, 0,
                   (size_t)VV * NN * DD * sizeof(u16) + (size_t)VV * NN * sizeof(float),
                   stream);
    prep_kernel<<<129, 128, 0, stream>>>(selfW, selfb, fusW, fusb, Wsf, c1);
    label_kernel<<<3125, 256, 0, stream>>>(feat, clsW, clsb, attW1, attb1, attW2, attb2,
                                           att_bias, natt, probs);
    scatter_kernel<<<187500, 256, 0, stream>>>(esrc, edst, ew, feat, aggB, wsum);
    relgate_kernel<<<dim3(3125, 3), 256, 0, stream>>>(relW, relb, gateW, gateb, aggB, wsum);
    vatt_kernel<<<dim3(3125, 3), 128, 0, stream>>>(aggB, view_pref, vattW1, vattb1,
                                                   vattW2, vattb2, vsc);
    combine_kernel<<<12500, 256, 0, stream>>>(aggB, vsc, natt);
    final_kernel<<<3125, 256, 0, stream>>>(feat, aggB, Wsf, c1, fusW, featW, featb,
                                           ln_g, ln_b, outp);
}